// Round 1
// baseline (1021.863 us; speedup 1.0000x reference)
//
#include <hip/hip_runtime.h>

#define S_TOK 3072   // 64*48
#define NHEADS 8

// ---------------- Pass A: QKV projection ----------------
// X [6144][512] @ W [512][1536] -> Q/K/V each [b][h][s][64]
__global__ __launch_bounds__(256) void ga_qkv_gemm(
    const float* __restrict__ X, const float* __restrict__ W,
    float* __restrict__ Q, float* __restrict__ K, float* __restrict__ V) {
  const int tid = threadIdx.x;
  const int ty = tid >> 4, tx = tid & 15;
  const int m0 = blockIdx.x * 64;
  const int n0 = blockIdx.y * 64;
  __shared__ float As[16][68];   // [k][m]
  __shared__ float Bs[16][68];   // [k][n]
  float acc[4][4] = {};
  const int lm = tid >> 2;   // 0..63
  const int lk4 = tid & 3;   // 0..3
  const int bk = tid >> 4;   // 0..15
  const int bn4 = tid & 15;  // 0..15
  for (int k0 = 0; k0 < 512; k0 += 16) {
    float4 a = *(const float4*)&X[(size_t)(m0 + lm) * 512 + k0 + lk4 * 4];
    As[lk4 * 4 + 0][lm] = a.x;
    As[lk4 * 4 + 1][lm] = a.y;
    As[lk4 * 4 + 2][lm] = a.z;
    As[lk4 * 4 + 3][lm] = a.w;
    *(float4*)&Bs[bk][bn4 * 4] =
        *(const float4*)&W[(size_t)(k0 + bk) * 1536 + n0 + bn4 * 4];
    __syncthreads();
#pragma unroll
    for (int kk = 0; kk < 16; ++kk) {
      float4 av = *(const float4*)&As[kk][ty * 4];
      float4 bv = *(const float4*)&Bs[kk][tx * 4];
      float aa[4] = {av.x, av.y, av.z, av.w};
      float bb[4] = {bv.x, bv.y, bv.z, bv.w};
#pragma unroll
      for (int i = 0; i < 4; ++i)
#pragma unroll
        for (int j = 0; j < 4; ++j)
          acc[i][j] = fmaf(aa[i], bb[j], acc[i][j]);
    }
    __syncthreads();
  }
  // scatter: col n = which*512 + h*64 + d ; all constant per block except d
  const int which = n0 >> 9;
  const int h = (n0 >> 6) & 7;
  const int b = m0 / S_TOK;
  const int s0 = m0 % S_TOK;
  float* dst = (which == 0) ? Q : (which == 1) ? K : V;
#pragma unroll
  for (int i = 0; i < 4; ++i) {
    float4 o = make_float4(acc[i][0], acc[i][1], acc[i][2], acc[i][3]);
    *(float4*)&dst[(size_t)((b * NHEADS + h) * S_TOK + s0 + ty * 4 + i) * 64 +
                   tx * 4] = o;
  }
}

// ---------------- Pass B: flash attention with 2D rel bias ----------------
// grid: (48 q-tiles, 16 b*h), block 256 (16x16), 4x4 outputs/thread
__global__ __launch_bounds__(256) void ga_attn(
    const float* __restrict__ Q, const float* __restrict__ K,
    const float* __restrict__ V, const float* __restrict__ rowtab,
    const float* __restrict__ coltab, float* __restrict__ CTX) {
  const int tid = threadIdx.x;
  const int ty = tid >> 4, tx = tid & 15;
  const int q0 = blockIdx.x * 64;
  const int bh = blockIdx.y;
  const int h = bh & 7;
  const int b = bh >> 3;
  __shared__ float Qs[64][68];  // [row][d]
  __shared__ float Kt[64][68];  // [d][col]  (transposed for conflict-free reads)
  __shared__ float Vs[64][68];  // [row][d]
  __shared__ float Ps[64][68];  // [qrow][kcol]
  __shared__ float rtab[127];
  __shared__ float ctab[95];
  for (int i = tid; i < 127; i += 256) rtab[i] = rowtab[i * 8 + h];
  for (int i = tid; i < 95; i += 256) ctab[i] = coltab[i * 8 + h];
  const float* Qp = Q + (size_t)bh * S_TOK * 64;
  const float* Kp = K + (size_t)bh * S_TOK * 64;
  const float* Vp = V + (size_t)bh * S_TOK * 64;
  const int lr = tid >> 4;   // 0..15
  const int ld4 = tid & 15;  // 0..15
#pragma unroll
  for (int t = 0; t < 4; ++t) {
    int r = lr + t * 16;
    *(float4*)&Qs[r][ld4 * 4] =
        *(const float4*)&Qp[(size_t)(q0 + r) * 64 + ld4 * 4];
  }
  float m_i[4], l_i[4], acc[4][4];
#pragma unroll
  for (int i = 0; i < 4; ++i) {
    m_i[i] = -1e30f;
    l_i[i] = 0.f;
#pragma unroll
    for (int j = 0; j < 4; ++j) acc[i][j] = 0.f;
  }
  int qr[4], qc[4];
#pragma unroll
  for (int i = 0; i < 4; ++i) {
    int qi = q0 + ty * 4 + i;
    qr[i] = qi / 48;
    qc[i] = qi - qr[i] * 48;
  }
  __syncthreads();
  for (int k0 = 0; k0 < S_TOK; k0 += 64) {
    // stage K (transposed) and V
#pragma unroll
    for (int t = 0; t < 4; ++t) {
      int r = lr + t * 16;
      float4 kv = *(const float4*)&Kp[(size_t)(k0 + r) * 64 + ld4 * 4];
      Kt[ld4 * 4 + 0][r] = kv.x;
      Kt[ld4 * 4 + 1][r] = kv.y;
      Kt[ld4 * 4 + 2][r] = kv.z;
      Kt[ld4 * 4 + 3][r] = kv.w;
      *(float4*)&Vs[r][ld4 * 4] =
          *(const float4*)&Vp[(size_t)(k0 + r) * 64 + ld4 * 4];
    }
    __syncthreads();
    // S = Q K^T (4x4 per thread), K-dim 64 in float4 chunks
    float sc[4][4] = {};
#pragma unroll
    for (int d4 = 0; d4 < 16; ++d4) {
      float qa[4][4], kb[4][4];
#pragma unroll
      for (int i = 0; i < 4; ++i) {
        float4 v = *(const float4*)&Qs[ty * 4 + i][d4 * 4];
        qa[i][0] = v.x; qa[i][1] = v.y; qa[i][2] = v.z; qa[i][3] = v.w;
      }
#pragma unroll
      for (int t = 0; t < 4; ++t) {
        float4 v = *(const float4*)&Kt[d4 * 4 + t][tx * 4];
        kb[t][0] = v.x; kb[t][1] = v.y; kb[t][2] = v.z; kb[t][3] = v.w;
      }
#pragma unroll
      for (int i = 0; i < 4; ++i)
#pragma unroll
        for (int j = 0; j < 4; ++j) {
          sc[i][j] = fmaf(qa[i][0], kb[0][j], sc[i][j]);
          sc[i][j] = fmaf(qa[i][1], kb[1][j], sc[i][j]);
          sc[i][j] = fmaf(qa[i][2], kb[2][j], sc[i][j]);
          sc[i][j] = fmaf(qa[i][3], kb[3][j], sc[i][j]);
        }
    }
    // scale + relative position bias
#pragma unroll
    for (int j = 0; j < 4; ++j) {
      int kj = k0 + tx * 4 + j;
      int kr = kj / 48;
      int kc = kj - kr * 48;
#pragma unroll
      for (int i = 0; i < 4; ++i)
        sc[i][j] = sc[i][j] * 0.125f + rtab[qr[i] - kr + 63] + ctab[qc[i] - kc + 47];
    }
    // online softmax: row reductions across the 16 tx lanes (same wave)
    float p[4][4];
#pragma unroll
    for (int i = 0; i < 4; ++i) {
      float r = fmaxf(fmaxf(sc[i][0], sc[i][1]), fmaxf(sc[i][2], sc[i][3]));
#pragma unroll
      for (int off = 1; off < 16; off <<= 1) r = fmaxf(r, __shfl_xor(r, off));
      float mnew = fmaxf(m_i[i], r);
      float scale = __expf(m_i[i] - mnew);
#pragma unroll
      for (int j = 0; j < 4; ++j) p[i][j] = __expf(sc[i][j] - mnew);
      float s = p[i][0] + p[i][1] + p[i][2] + p[i][3];
#pragma unroll
      for (int off = 1; off < 16; off <<= 1) s += __shfl_xor(s, off);
      l_i[i] = l_i[i] * scale + s;
      m_i[i] = mnew;
#pragma unroll
      for (int j = 0; j < 4; ++j) acc[i][j] *= scale;
      *(float4*)&Ps[ty * 4 + i][tx * 4] =
          make_float4(p[i][0], p[i][1], p[i][2], p[i][3]);
    }
    __syncthreads();
    // O += P @ V
#pragma unroll
    for (int k4 = 0; k4 < 16; ++k4) {
      float pa[4][4], vb[4][4];
#pragma unroll
      for (int i = 0; i < 4; ++i) {
        float4 v = *(const float4*)&Ps[ty * 4 + i][k4 * 4];
        pa[i][0] = v.x; pa[i][1] = v.y; pa[i][2] = v.z; pa[i][3] = v.w;
      }
#pragma unroll
      for (int t = 0; t < 4; ++t) {
        float4 v = *(const float4*)&Vs[k4 * 4 + t][tx * 4];
        vb[t][0] = v.x; vb[t][1] = v.y; vb[t][2] = v.z; vb[t][3] = v.w;
      }
#pragma unroll
      for (int i = 0; i < 4; ++i)
#pragma unroll
        for (int j = 0; j < 4; ++j) {
          acc[i][j] = fmaf(pa[i][0], vb[0][j], acc[i][j]);
          acc[i][j] = fmaf(pa[i][1], vb[1][j], acc[i][j]);
          acc[i][j] = fmaf(pa[i][2], vb[2][j], acc[i][j]);
          acc[i][j] = fmaf(pa[i][3], vb[3][j], acc[i][j]);
        }
    }
    __syncthreads();
  }
  // epilogue: normalize, write context [b*S+s][h*64+d]
#pragma unroll
  for (int i = 0; i < 4; ++i) {
    float inv = 1.0f / l_i[i];
    float4 o = make_float4(acc[i][0] * inv, acc[i][1] * inv, acc[i][2] * inv,
                           acc[i][3] * inv);
    *(float4*)&CTX[(size_t)(b * S_TOK + q0 + ty * 4 + i) * 512 + h * 64 +
                   tx * 4] = o;
  }
}

// ---------------- Pass C: output projection ----------------
// CTX [6144][512] @ W [512][512] -> out [6144][512]
__global__ __launch_bounds__(256) void ga_out_gemm(
    const float* __restrict__ A, const float* __restrict__ W,
    float* __restrict__ Out) {
  const int tid = threadIdx.x;
  const int ty = tid >> 4, tx = tid & 15;
  const int m0 = blockIdx.x * 64;
  const int n0 = blockIdx.y * 64;
  __shared__ float As[16][68];
  __shared__ float Bs[16][68];
  float acc[4][4] = {};
  const int lm = tid >> 2, lk4 = tid & 3;
  const int bk = tid >> 4, bn4 = tid & 15;
  for (int k0 = 0; k0 < 512; k0 += 16) {
    float4 a = *(const float4*)&A[(size_t)(m0 + lm) * 512 + k0 + lk4 * 4];
    As[lk4 * 4 + 0][lm] = a.x;
    As[lk4 * 4 + 1][lm] = a.y;
    As[lk4 * 4 + 2][lm] = a.z;
    As[lk4 * 4 + 3][lm] = a.w;
    *(float4*)&Bs[bk][bn4 * 4] =
        *(const float4*)&W[(size_t)(k0 + bk) * 512 + n0 + bn4 * 4];
    __syncthreads();
#pragma unroll
    for (int kk = 0; kk < 16; ++kk) {
      float4 av = *(const float4*)&As[kk][ty * 4];
      float4 bv = *(const float4*)&Bs[kk][tx * 4];
      float aa[4] = {av.x, av.y, av.z, av.w};
      float bb[4] = {bv.x, bv.y, bv.z, bv.w};
#pragma unroll
      for (int i = 0; i < 4; ++i)
#pragma unroll
        for (int j = 0; j < 4; ++j)
          acc[i][j] = fmaf(aa[i], bb[j], acc[i][j]);
    }
    __syncthreads();
  }
#pragma unroll
  for (int i = 0; i < 4; ++i) {
    float4 o = make_float4(acc[i][0], acc[i][1], acc[i][2], acc[i][3]);
    *(float4*)&Out[(size_t)(m0 + ty * 4 + i) * 512 + n0 + tx * 4] = o;
  }
}

extern "C" void kernel_launch(void* const* d_in, const int* in_sizes, int n_in,
                              void* d_out, int out_size, void* d_ws,
                              size_t ws_size, hipStream_t stream) {
  const float* x = (const float*)d_in[0];       // [2,64,48,512]
  const float* w_qkv = (const float*)d_in[1];   // [512,1536]
  const float* w_out = (const float*)d_in[2];   // [512,512]
  const float* rrow = (const float*)d_in[3];    // [127,8]
  const float* rcol = (const float*)d_in[4];    // [95,8]
  float* out = (float*)d_out;                   // [6144,512]

  const size_t QSZ = (size_t)2 * NHEADS * S_TOK * 64;  // 3,145,728 floats
  float* ws = (float*)d_ws;
  float* Q = ws;
  float* K = ws + QSZ;
  float* V = ws + 2 * QSZ;
  float* CTX = ws + 3 * QSZ;  // [6144][512]

  ga_qkv_gemm<<<dim3(96, 24), 256, 0, stream>>>(x, w_qkv, Q, K, V);
  ga_attn<<<dim3(48, 16), 256, 0, stream>>>(Q, K, V, rrow, rcol, CTX);
  ga_out_gemm<<<dim3(96, 8), 256, 0, stream>>>(CTX, w_out, out);
}

// Round 2
// 450.899 us; speedup vs baseline: 2.2663x; 2.2663x over previous
//
#include <hip/hip_runtime.h>

#define S_TOK 3072   // 64*48
#define NHEADS 8

typedef __attribute__((ext_vector_type(8))) short short8;
typedef __attribute__((ext_vector_type(4))) float floatx4;
typedef __attribute__((ext_vector_type(4))) unsigned short ushortx4;

__device__ __forceinline__ unsigned short f2bf(float f) {
  union { float f; unsigned u; } v; v.f = f;
  unsigned r = v.u + 0x7fffu + ((v.u >> 16) & 1u);   // RTN-even
  return (unsigned short)(r >> 16);
}

// ---------------- Pass A: QKV projection (f32 math, bf16 out) ----------------
// X [6144][512] @ W [512][1536] -> Q,K [bh][s][64] bf16 ; Vt [bh][64][3072] bf16
__global__ __launch_bounds__(256) void ga_qkv_gemm(
    const float* __restrict__ X, const float* __restrict__ W,
    unsigned short* __restrict__ Q, unsigned short* __restrict__ K,
    unsigned short* __restrict__ Vt) {
  const int tid = threadIdx.x;
  const int ty = tid >> 4, tx = tid & 15;
  const int m0 = blockIdx.x * 64;
  const int n0 = blockIdx.y * 64;
  __shared__ float As[16][68];   // [k][m]
  __shared__ float Bs[16][68];   // [k][n]
  float acc[4][4] = {};
  const int lm = tid >> 2;   // 0..63
  const int lk4 = tid & 3;   // 0..3
  const int bk = tid >> 4;   // 0..15
  const int bn4 = tid & 15;  // 0..15
  for (int k0 = 0; k0 < 512; k0 += 16) {
    float4 a = *(const float4*)&X[(size_t)(m0 + lm) * 512 + k0 + lk4 * 4];
    As[lk4 * 4 + 0][lm] = a.x;
    As[lk4 * 4 + 1][lm] = a.y;
    As[lk4 * 4 + 2][lm] = a.z;
    As[lk4 * 4 + 3][lm] = a.w;
    *(float4*)&Bs[bk][bn4 * 4] =
        *(const float4*)&W[(size_t)(k0 + bk) * 1536 + n0 + bn4 * 4];
    __syncthreads();
#pragma unroll
    for (int kk = 0; kk < 16; ++kk) {
      float4 av = *(const float4*)&As[kk][ty * 4];
      float4 bv = *(const float4*)&Bs[kk][tx * 4];
      float aa[4] = {av.x, av.y, av.z, av.w};
      float bb[4] = {bv.x, bv.y, bv.z, bv.w};
#pragma unroll
      for (int i = 0; i < 4; ++i)
#pragma unroll
        for (int j = 0; j < 4; ++j)
          acc[i][j] = fmaf(aa[i], bb[j], acc[i][j]);
    }
    __syncthreads();
  }
  const int which = n0 >> 9;        // 0=Q 1=K 2=V
  const int h = (n0 >> 6) & 7;
  const int b = m0 / S_TOK;
  const int s0 = m0 % S_TOK;
  const int bh = b * NHEADS + h;
  if (which < 2) {
    unsigned short* dst = (which == 0 ? Q : K) + (size_t)bh * S_TOK * 64;
#pragma unroll
    for (int i = 0; i < 4; ++i) {
      ushortx4 o = {f2bf(acc[i][0]), f2bf(acc[i][1]), f2bf(acc[i][2]),
                    f2bf(acc[i][3])};
      *(ushortx4*)&dst[(size_t)(s0 + ty * 4 + i) * 64 + tx * 4] = o;
    }
  } else {
    unsigned short* dst = Vt + (size_t)bh * 64 * S_TOK;
#pragma unroll
    for (int j = 0; j < 4; ++j) {
      int d = tx * 4 + j;
      ushortx4 o = {f2bf(acc[0][j]), f2bf(acc[1][j]), f2bf(acc[2][j]),
                    f2bf(acc[3][j])};
      *(ushortx4*)&dst[(size_t)d * S_TOK + s0 + ty * 4] = o;
    }
  }
}

// ---------------- Pass B: MFMA flash attention with 2D rel bias --------------
// grid (48 qtiles, 16 bh), block 256 = 4 waves; each wave owns 16 q-rows.
// K-tile = 64 keys. All softmax in exp2-space (tables pre-scaled by log2e).
__global__ __launch_bounds__(256) void ga_attn_mfma(
    const unsigned short* __restrict__ Q, const unsigned short* __restrict__ K,
    const unsigned short* __restrict__ Vt, const float* __restrict__ rowtab,
    const float* __restrict__ coltab, float* __restrict__ CTX) {
  const int tid = threadIdx.x;
  const int w = tid >> 6;        // wave 0..3
  const int l = tid & 63;        // lane
  const int g = l >> 4;          // lane group 0..3
  const int ln = l & 15;         // lane 0..15
  const int q0 = blockIdx.x * 64;
  const int bh = blockIdx.y;
  const int h = bh & 7;
  const int b = bh >> 3;

  __shared__ float rtab[127];
  __shared__ float ctab[95];
  __shared__ unsigned short Plds[4][1024];  // per-wave 16x64 bf16, swizzled
  for (int i = tid; i < 127; i += 256) rtab[i] = rowtab[i * 8 + h] * 1.44269504f;
  for (int i = tid; i < 95; i += 256) ctab[i] = coltab[i * 8 + h] * 1.44269504f;
  __syncthreads();

  const unsigned short* Qp = Q + (size_t)bh * S_TOK * 64;
  const unsigned short* Kp = K + (size_t)bh * S_TOK * 64;
  const unsigned short* Vp = Vt + (size_t)bh * 64 * S_TOK;

  // A-frag of Q for this wave's 16 rows (lane: row=ln, k = g*8..+7 per chunk)
  const int qrow = q0 + w * 16 + ln;
  short8 qf0 = *(const short8*)&Qp[(size_t)qrow * 64 + g * 8];
  short8 qf1 = *(const short8*)&Qp[(size_t)qrow * 64 + 32 + g * 8];

  // this lane's 4 softmax rows: q = q0 + w*16 + g*4 + r
  int qr[4], qc[4];
#pragma unroll
  for (int r = 0; r < 4; ++r) {
    int q = q0 + w * 16 + g * 4 + r;
    qr[r] = q / 48;
    qc[r] = q - qr[r] * 48;
  }

  floatx4 o_acc[4] = {floatx4{0.f, 0.f, 0.f, 0.f}, floatx4{0.f, 0.f, 0.f, 0.f},
                      floatx4{0.f, 0.f, 0.f, 0.f}, floatx4{0.f, 0.f, 0.f, 0.f}};
  float m_i[4] = {-1e30f, -1e30f, -1e30f, -1e30f};
  float l_i[4] = {0.f, 0.f, 0.f, 0.f};

  for (int k0 = 0; k0 < S_TOK; k0 += 64) {
    // ---- S = Q K^T : 4 key-tiles x 2 K-chunks, B-frags straight from global
    floatx4 s_acc[4] = {floatx4{0.f, 0.f, 0.f, 0.f}, floatx4{0.f, 0.f, 0.f, 0.f},
                        floatx4{0.f, 0.f, 0.f, 0.f}, floatx4{0.f, 0.f, 0.f, 0.f}};
#pragma unroll
    for (int t = 0; t < 4; ++t) {
      const unsigned short* kp = &Kp[(size_t)(k0 + t * 16 + ln) * 64 + g * 8];
      short8 kf0 = *(const short8*)kp;
      short8 kf1 = *(const short8*)(kp + 32);
      s_acc[t] = __builtin_amdgcn_mfma_f32_16x16x32_bf16(qf0, kf0, s_acc[t], 0, 0, 0);
      s_acc[t] = __builtin_amdgcn_mfma_f32_16x16x32_bf16(qf1, kf1, s_acc[t], 0, 0, 0);
    }
    // ---- scale (x log2e) + rel-pos bias; C layout: row=g*4+r, col=t*16+ln
    float p[4][4];
#pragma unroll
    for (int t = 0; t < 4; ++t) {
      int k = k0 + t * 16 + ln;
      int kr = k / 48;
      int kc = k - kr * 48;
#pragma unroll
      for (int r = 0; r < 4; ++r)
        p[t][r] = s_acc[t][r] * 0.18033688f + rtab[qr[r] - kr + 63] +
                  ctab[qc[r] - kc + 47];
    }
    // ---- online softmax per row (row's 64 values: 4 tiles in-lane x 16 lanes)
#pragma unroll
    for (int r = 0; r < 4; ++r) {
      float mx = fmaxf(fmaxf(p[0][r], p[1][r]), fmaxf(p[2][r], p[3][r]));
      mx = fmaxf(mx, __shfl_xor(mx, 1));
      mx = fmaxf(mx, __shfl_xor(mx, 2));
      mx = fmaxf(mx, __shfl_xor(mx, 4));
      mx = fmaxf(mx, __shfl_xor(mx, 8));
      float mnew = fmaxf(m_i[r], mx);
      float alpha = __builtin_amdgcn_exp2f(m_i[r] - mnew);
      m_i[r] = mnew;
      float s = 0.f;
#pragma unroll
      for (int t = 0; t < 4; ++t) {
        float e = __builtin_amdgcn_exp2f(p[t][r] - mnew);
        p[t][r] = e;
        s += e;
      }
      s += __shfl_xor(s, 1);
      s += __shfl_xor(s, 2);
      s += __shfl_xor(s, 4);
      s += __shfl_xor(s, 8);
      l_i[r] = l_i[r] * alpha + s;
      o_acc[0][r] *= alpha;
      o_acc[1][r] *= alpha;
      o_acc[2][r] *= alpha;
      o_acc[3][r] *= alpha;
    }
    // ---- P (bf16) -> per-wave LDS, XOR-swizzled; then read back as A-frags
#pragma unroll
    for (int t = 0; t < 4; ++t)
#pragma unroll
      for (int r = 0; r < 4; ++r) {
        int row = g * 4 + r;
        int col = t * 16 + ln;
        Plds[w][(row * 64 + col) ^ ((row & 7) << 3)] = f2bf(p[t][r]);
      }
    short8 pf0 = *(const short8*)&Plds[w][(ln * 64 + g * 8) ^ ((ln & 7) << 3)];
    short8 pf1 = *(const short8*)&Plds[w][(ln * 64 + 32 + g * 8) ^ ((ln & 7) << 3)];
    // ---- O += P V : B-frags from transposed V (contiguous in key)
#pragma unroll
    for (int t = 0; t < 4; ++t) {
      const unsigned short* vp = &Vp[(size_t)(t * 16 + ln) * S_TOK + k0 + g * 8];
      short8 vf0 = *(const short8*)vp;
      short8 vf1 = *(const short8*)(vp + 32);
      o_acc[t] = __builtin_amdgcn_mfma_f32_16x16x32_bf16(pf0, vf0, o_acc[t], 0, 0, 0);
      o_acc[t] = __builtin_amdgcn_mfma_f32_16x16x32_bf16(pf1, vf1, o_acc[t], 0, 0, 0);
    }
  }
  // ---- epilogue: normalize, write CTX f32 [b*S+q][h*64+d]
#pragma unroll
  for (int r = 0; r < 4; ++r) {
    float inv = 1.0f / l_i[r];
    int q = q0 + w * 16 + g * 4 + r;
    float* dst = &CTX[((size_t)(b * S_TOK + q)) * 512 + h * 64 + ln];
    dst[0] = o_acc[0][r] * inv;
    dst[16] = o_acc[1][r] * inv;
    dst[32] = o_acc[2][r] * inv;
    dst[48] = o_acc[3][r] * inv;
  }
}

// ---------------- Pass C: output projection (f32) ----------------
__global__ __launch_bounds__(256) void ga_out_gemm(
    const float* __restrict__ A, const float* __restrict__ W,
    float* __restrict__ Out) {
  const int tid = threadIdx.x;
  const int ty = tid >> 4, tx = tid & 15;
  const int m0 = blockIdx.x * 64;
  const int n0 = blockIdx.y * 64;
  __shared__ float As[16][68];
  __shared__ float Bs[16][68];
  float acc[4][4] = {};
  const int lm = tid >> 2, lk4 = tid & 3;
  const int bk = tid >> 4, bn4 = tid & 15;
  for (int k0 = 0; k0 < 512; k0 += 16) {
    float4 a = *(const float4*)&A[(size_t)(m0 + lm) * 512 + k0 + lk4 * 4];
    As[lk4 * 4 + 0][lm] = a.x;
    As[lk4 * 4 + 1][lm] = a.y;
    As[lk4 * 4 + 2][lm] = a.z;
    As[lk4 * 4 + 3][lm] = a.w;
    *(float4*)&Bs[bk][bn4 * 4] =
        *(const float4*)&W[(size_t)(k0 + bk) * 512 + n0 + bn4 * 4];
    __syncthreads();
#pragma unroll
    for (int kk = 0; kk < 16; ++kk) {
      float4 av = *(const float4*)&As[kk][ty * 4];
      float4 bv = *(const float4*)&Bs[kk][tx * 4];
      float aa[4] = {av.x, av.y, av.z, av.w};
      float bb[4] = {bv.x, bv.y, bv.z, bv.w};
#pragma unroll
      for (int i = 0; i < 4; ++i)
#pragma unroll
        for (int j = 0; j < 4; ++j)
          acc[i][j] = fmaf(aa[i], bb[j], acc[i][j]);
    }
    __syncthreads();
  }
#pragma unroll
  for (int i = 0; i < 4; ++i) {
    float4 o = make_float4(acc[i][0], acc[i][1], acc[i][2], acc[i][3]);
    *(float4*)&Out[(size_t)(m0 + ty * 4 + i) * 512 + n0 + tx * 4] = o;
  }
}

extern "C" void kernel_launch(void* const* d_in, const int* in_sizes, int n_in,
                              void* d_out, int out_size, void* d_ws,
                              size_t ws_size, hipStream_t stream) {
  const float* x = (const float*)d_in[0];       // [2,64,48,512]
  const float* w_qkv = (const float*)d_in[1];   // [512,1536]
  const float* w_out = (const float*)d_in[2];   // [512,512]
  const float* rrow = (const float*)d_in[3];    // [127,8]
  const float* rcol = (const float*)d_in[4];    // [95,8]
  float* out = (float*)d_out;                   // [6144,512]

  const size_t QSZ = (size_t)2 * NHEADS * S_TOK * 64;  // 3,145,728 elems
  unsigned short* Q = (unsigned short*)d_ws;
  unsigned short* K = Q + QSZ;
  unsigned short* Vt = K + QSZ;
  float* CTX = (float*)(Vt + QSZ);  // [6144][512] f32

  ga_qkv_gemm<<<dim3(96, 24), 256, 0, stream>>>(x, w_qkv, Q, K, Vt);
  ga_attn_mfma<<<dim3(48, 16), 256, 0, stream>>>(Q, K, Vt, rrow, rcol, CTX);
  ga_out_gemm<<<dim3(96, 8), 256, 0, stream>>>(CTX, w_out, out);
}